// Round 3
// baseline (96.515 us; speedup 1.0000x reference)
//
#include <hip/hip_runtime.h>

#define NC   8
#define MTOT 17408   // NSPOKE*NVEC = 34*512

typedef __attribute__((ext_vector_type(8)))  short short8;
typedef __attribute__((ext_vector_type(16))) float f32x16;

typedef __attribute__((address_space(3))) unsigned       lds_uint;
typedef const __attribute__((address_space(1))) unsigned glb_uint;

static __device__ __forceinline__ short f2bf(float f) {
    union { float f; unsigned u; } v; v.f = f;
    return (short)((v.u + 0x7fffu + ((v.u >> 16) & 1u)) >> 16);
}

// K1: src[c][a][b] = (Xr + i Xi) * (Cr + i Ci) -> bf16 planes Sr, Si
__global__ __launch_bounds__(256) void build_src(
        const float* __restrict__ X, const float* __restrict__ C,
        short* __restrict__ Sr, short* __restrict__ Si) {
    int idx = blockIdx.x * 256 + threadIdx.x;   // [0, 8*65536)
    int ab = idx & 65535;
    float xr = X[ab * 2 + 0], xi = X[ab * 2 + 1];
    float cr = C[idx * 2 + 0], ci = C[idx * 2 + 1];
    Sr[idx] = f2bf(xr * cr - xi * ci);
    Si[idx] = f2bf(xr * ci + xi * cr);
}

// K2: Eb table in MFMA-B fragment order for 32x32x16.
// Layout: EbT[((kt*2+plane)*16 + ks)*512 + lane*8 + j]
//   = plane of exp(-i * t_k * b'), k = kt*32 + (lane&31),
//     b' = ks*16 + (lane>>5)*8 + j - 128.
__global__ __launch_bounds__(256) void build_ebt(
        const float* __restrict__ angles, short* __restrict__ EbT) {
    int gid  = blockIdx.x * 256 + threadIdx.x;   // [0, 544*1024)
    int kt   = gid >> 10;
    int r    = gid & 1023;
    int ks   = r >> 6;
    int lane = r & 63;
    int k    = kt * 32 + (lane & 31);
    float t  = angles[k * 2 + 1];
    short8 re, im;
    #pragma unroll
    for (int j = 0; j < 8; ++j) {
        float xb = (float)(ks * 16 + (lane >> 5) * 8 + j - 128);
        float sn, cs;
        __sincosf(t * xb, &sn, &cs);
        re[j] = f2bf(cs);
        im[j] = f2bf(-sn);
    }
    short* base = EbT + (size_t)(kt * 32 + ks) * 512 + lane * 8;
    *(short8*)(base)        = re;
    *(short8*)(base + 8192) = im;    // plane stride within kt block = 16*512
}

// K3: y[c,k] = w[k] * sum_a Ea[k,a] * sum_b src[c,a,b] * Eb[k,b]
// Block = 4 waves x 32 k-cols = 128 k, one coil. mfma_f32_32x32x16_bf16.
// A-tiles (32 a-rows x 256 b x 2 planes = 32KB) double-buffered in LDS,
// staged via global_load_lds with pre-swizzled source (slot = chunk^(row&7)).
template<int USE_TABLE>
__global__ __launch_bounds__(256, 2) void nufft_fwd(
        const float* __restrict__ angles, const float* __restrict__ w,
        const short* __restrict__ SrP, const short* __restrict__ SiP,
        const short* __restrict__ EbT, float* __restrict__ out) {
    __shared__ char lds[65536];

    const int tid  = threadIdx.x;
    const int lane = tid & 63;
    const int wv   = tid >> 6;
    const int c    = blockIdx.y;
    const int col  = lane & 31;      // MFMA: A-row / B-col / D-col
    const int hi   = lane >> 5;      // MFMA: K-half selector
    const int kt   = blockIdx.x * 4 + wv;
    const int k    = kt * 32 + col;
    const float s  = angles[k * 2 + 0];

    const short* Sr = SrP + c * 65536;
    const short* Si = SiP + c * 65536;

    // B fragments: Eb for this wave's 32 k-cols, all 256 b (16 K-steps).
    short8 Br[16], Bi[16];
    if constexpr (USE_TABLE) {
        const short* tb = EbT + (size_t)(kt * 32) * 512 + lane * 8;
        #pragma unroll
        for (int ks = 0; ks < 16; ++ks) {
            Br[ks] = *(const short8*)(tb + ks * 512);
            Bi[ks] = *(const short8*)(tb + 8192 + ks * 512);
        }
    } else {
        const float t = angles[k * 2 + 1];
        #pragma unroll
        for (int ks = 0; ks < 16; ++ks) {
            short8 re, im;
            #pragma unroll
            for (int j = 0; j < 8; ++j) {
                float xb = (float)(ks * 16 + hi * 8 + j - 128);
                float sn, cs;
                __sincosf(t * xb, &sn, &cs);
                re[j] = f2bf(cs);
                im[j] = f2bf(-sn);
            }
            Br[ks] = re; Bi[ks] = im;
        }
    }

    // Stage a-tile `at` (32 rows x 256 b x 2 planes = 2048 x 16B chunks)
    // into LDS half. Linear LDS dest; source chunk pre-swizzled (rule #21).
    auto stage = [&](int at, int half) {
        #pragma unroll
        for (int it = 0; it < 8; ++it) {
            int L   = it * 256 + tid;          // linear 16B-chunk id
            int row = (L >> 5) & 31;
            int cb  = (L & 31) ^ (row & 7);    // global chunk for this slot
            const short* g = ((L >> 10) ? Si : Sr) + (at * 32 + row) * 256 + cb * 8;
            __builtin_amdgcn_global_load_lds(
                (glb_uint*)g,
                (lds_uint*)(lds + half * 32768 + (it * 256 + (tid & ~63)) * 16),
                16, 0, 0);
        }
    };

    float yr = 0.f, yi = 0.f;

    stage(0, 0);
    __syncthreads();

    for (int at = 0; at < 8; ++at) {
        const int cur = at & 1;
        if (at < 7) stage(at + 1, cur ^ 1);

        const char* buf = lds + cur * 32768;
        f32x16 P1 = {0.f}, P2 = {0.f}, P3 = {0.f}, P4 = {0.f};
        const int rowoff = col * 512;
        const int swz    = col & 7;
        #pragma unroll
        for (int ks = 0; ks < 16; ++ks) {
            int slot = ((ks * 2 + hi) ^ swz) << 4;
            short8 Arf = *(const short8*)(buf + rowoff + slot);
            short8 Aif = *(const short8*)(buf + 16384 + rowoff + slot);
            P1 = __builtin_amdgcn_mfma_f32_32x32x16_bf16(Arf, Br[ks], P1, 0, 0, 0);
            P2 = __builtin_amdgcn_mfma_f32_32x32x16_bf16(Aif, Bi[ks], P2, 0, 0, 0);
            P3 = __builtin_amdgcn_mfma_f32_32x32x16_bf16(Arf, Bi[ks], P3, 0, 0, 0);
            P4 = __builtin_amdgcn_mfma_f32_32x32x16_bf16(Aif, Br[ks], P4, 0, 0, 0);
        }
        // Epilogue: D col = lane&31 (k), row = (reg&3)+8*(reg>>2)+4*hi (a).
        #pragma unroll
        for (int reg = 0; reg < 16; ++reg) {
            int ap = at * 32 + (reg & 3) + 8 * (reg >> 2) + 4 * hi - 128;
            float Tr = P1[reg] - P2[reg];
            float Ti = P3[reg] + P4[reg];
            float sn, cs;
            __sincosf(s * (float)ap, &sn, &cs);
            yr += cs * Tr + sn * Ti;   // Ea = cs - i*sn
            yi += cs * Ti - sn * Tr;
        }
        __syncthreads();
    }

    // Lanes l and l+32 hold disjoint a-rows of the same k-col.
    yr += __shfl_xor(yr, 32);
    yi += __shfl_xor(yi, 32);

    if (hi == 0) {
        float wk = w[k];
        out[((size_t)c * MTOT + k) * 2 + 0] = yr * wk;
        out[((size_t)c * MTOT + k) * 2 + 1] = yi * wk;
    }
}

extern "C" void kernel_launch(void* const* d_in, const int* in_sizes, int n_in,
                              void* d_out, int out_size, void* d_ws, size_t ws_size,
                              hipStream_t stream) {
    const float* X      = (const float*)d_in[0];
    const float* angles = (const float*)d_in[1];
    const float* C      = (const float*)d_in[2];
    const float* w      = (const float*)d_in[3];
    float* out = (float*)d_out;

    short* Sr  = (short*)d_ws;           // 1 MB
    short* Si  = Sr + NC * 65536;        // 1 MB
    short* EbT = Si + NC * 65536;        // 17.8 MB (fragment-order Eb table)

    size_t need = ((size_t)NC * 65536 * 2 + (size_t)MTOT * 512) * sizeof(short);
    const bool use_table = ws_size >= need;

    build_src<<<dim3(NC * 65536 / 256), dim3(256), 0, stream>>>(X, C, Sr, Si);

    dim3 grid(MTOT / 128, NC);           // (136, 8)
    if (use_table) {
        build_ebt<<<dim3(MTOT * 32 / 256), dim3(256), 0, stream>>>(angles, EbT);
        nufft_fwd<1><<<grid, dim3(256), 0, stream>>>(angles, w, Sr, Si, EbT, out);
    } else {
        nufft_fwd<0><<<grid, dim3(256), 0, stream>>>(angles, w, Sr, Si, nullptr, out);
    }
}